// Round 9
// baseline (1587.375 us; speedup 1.0000x reference)
//
#include <hip/hip_runtime.h>

// LSTM (B=256, T=256, F=128, H=1024) + sigmoid + FC(1024->128).
// Persistent 256-WG x 512-thread kernel (8 waves = 2 waves/SIMD for TLP).
// Per step t: gates[32rows x 128gatecols] = [h|x](fp16) x W_cat^T (fp16,
// register-resident, K-split 8 ways) + bias; per-lane i,f,g,o -> c,h (fp32).
//
// R9 key change: h exchanged in MFMA FRAGMENT LAYOUT at the MALL.
//   hb[buf][rg][chunk 0..63][lane 0..63][16B], chunk = 16 k-values:
//   byte(chunk,l,j) = h[row = l&31][col = chunk*16 + (l>>5)*8 + j].
//   Consumers load fragments DIRECTLY to registers (2 x u64 agent loads per
//   chunk, 1KB/instruction coalesced) -> no LDS stage round trip at all.
//   Producers write their 32x32 tile as 2 contiguous 1KB chunks (512 x 4B
//   coalesced agent stores, sourced from the hst LDS tile).
// Wave w consumes h chunks [8w,8w+8) + x chunk w (k [16w,+16) of x).
// Reduce: 8-wave single-round in 128KB LDS (float4 writes, float2 reads).
// Cell split: wave w -> c-group cw=w&3, half ihalf=w>>2: rows
// 8*cw + 4*hi + 2*ihalf + {0,1} (2 rows/thread).
// Barrier: RMW-free epoch flags (R5). Wave w polls only its 4 producers
// cg' in [4w,4w+4). Union over 8 waves = all 32 -> transitivity: flag[p]=t
// implies p passed poll(t-2) i.e. all 32 flags >= t-1 -> all step-(t-2)
// reads done -> overwriting hb[(t+1)&3] (last read step t-3) is safe.
// MFMA mfma_f32_32x32x16_f16: A lane row=l&31,k=(l>>5)*8+j; B col=l&31,
// same k; C col=l&31, row=(reg&3)+8*(reg>>2)+4*(l>>5) [m101].

typedef _Float16 f16x8 __attribute__((ext_vector_type(8)));
typedef float f32x16 __attribute__((ext_vector_type(16)));
typedef unsigned long long u64;
struct U128 { u64 a, b; };

#define SCOPE_AGENT __HIP_MEMORY_SCOPE_AGENT

#define WS_WP    0ull
#define WS_BIAS  9437184ull
#define WS_XT    (WS_BIAS + 16384ull)
#define WS_HB    (WS_XT + 16777216ull)          // 4 buffers x 524288B
#define WS_SIGH  (WS_HB + 4ull * 524288ull)
#define WS_BAR   (WS_SIGH + 1048576ull)

__device__ __forceinline__ unsigned short f2h(float f) {
  _Float16 h = (_Float16)f;
  return __builtin_bit_cast(unsigned short, h);
}

__device__ __forceinline__ float fast_sig(float x) {
  return __builtin_amdgcn_rcpf(1.f + __expf(-x));
}
__device__ __forceinline__ float fast_tanh(float x) {
  return __builtin_fmaf(2.f, fast_sig(2.f * x), -1.f);
}

// Agent-coherent 16B fragment load (two u64 relaxed atomics -> MALL).
__device__ __forceinline__ int4 load_frag(const char* p) {
  U128 u;
  u.a = __hip_atomic_load((const u64*)p,       __ATOMIC_RELAXED, SCOPE_AGENT);
  u.b = __hip_atomic_load((const u64*)(p + 8), __ATOMIC_RELAXED, SCOPE_AGENT);
  return __builtin_bit_cast(int4, u);
}

// Pack W_cat into per-(cg,w,n,q,lane) MFMA B-fragments.
// flat i = ((((cg*8 + w)*4 + n)*9 + q)*64 + l)*8 + j
//   gcol = n*1024 + cg*32 + (l&31); khi = (l>>5)*8 + j
//   q<8: k = (w*8+q)*16 + khi -> W_hh[gcol][k]
//   q=8: f = w*16 + khi       -> W_ih[gcol][f]
__global__ void prep_pack(const float* __restrict__ W_ih, const float* __restrict__ W_hh,
                          const float* __restrict__ b_ih, const float* __restrict__ b_hh,
                          unsigned short* __restrict__ wp, float* __restrict__ bias) {
  unsigned i = blockIdx.x * 256u + threadIdx.x;
  if (i < 4718592u) {
    unsigned j = i & 7u;
    unsigned l = (i >> 3) & 63u;
    unsigned rest = i >> 9;
    unsigned q = rest % 9u;
    unsigned rest2 = rest / 9u;
    unsigned n = rest2 & 3u;
    unsigned rest3 = rest2 >> 2;
    unsigned w = rest3 & 7u;
    unsigned cg = rest3 >> 3;
    unsigned gcol = n * 1024u + cg * 32u + (l & 31u);
    unsigned khi = (l >> 5) * 8u + j;
    float v;
    if (q < 8u) {
      unsigned k = (w * 8u + q) * 16u + khi;
      v = W_hh[(size_t)gcol * 1024u + k];
    } else {
      unsigned f = w * 16u + khi;
      v = W_ih[(size_t)gcol * 128u + f];
    }
    wp[i] = f2h(v);
  }
  if (i < 4096u) bias[i] = b_ih[i] + b_hh[i];
}

// x[B][T][F] fp32 -> xT[T][B][F] fp16 ; h0 -> hb buffer 0 in FRAGMENT layout;
// zero flags.
__global__ void prep_misc(const float* __restrict__ x, const float* __restrict__ h0,
                          unsigned short* __restrict__ xT, unsigned short* __restrict__ hb0,
                          unsigned* __restrict__ bar) {
  unsigned i = blockIdx.x * 256u + threadIdx.x;
  if (i < 8388608u) {
    unsigned f = i & 127u;
    unsigned b = (i >> 7) & 255u;
    unsigned t = i >> 15;
    xT[i] = f2h(x[((size_t)b * 256u + t) * 128u + f]);
  }
  if (i < 262144u) {
    // hb0[rg][chunk][l][j] = h0[rg*32 + (l&31)][chunk*16 + (l>>5)*8 + j]
    unsigned j = i & 7u;
    unsigned l = (i >> 3) & 63u;
    unsigned chunk = (i >> 9) & 63u;
    unsigned rg = i >> 15;
    unsigned row = rg * 32u + (l & 31u);
    unsigned col = chunk * 16u + (l >> 5) * 8u + j;
    hb0[i] = f2h(h0[row * 1024u + col]);
  }
  if (i < 768u) bar[i] = 0u;
}

__launch_bounds__(512, 1)
__global__ void lstm_main(const unsigned short* __restrict__ wp,
                          const float* __restrict__ bias,
                          const unsigned short* __restrict__ xT,
                          unsigned short* __restrict__ hb,
                          const float* __restrict__ c0,
                          float* __restrict__ sigh,
                          unsigned* __restrict__ bar) {
  extern __shared__ char lds[];
  float4* redv  = (float4*)lds;                          // 128 KB reduce
  float2* redv2 = (float2*)lds;
  unsigned short* hst = (unsigned short*)(lds + 131072); // 2 KB h tile

  const unsigned tid = threadIdx.x;
  const unsigned wg  = blockIdx.x;
  const unsigned w   = tid >> 6;       // wave 0..7 (K-slice owner)
  const unsigned l   = tid & 63u;
  const unsigned rg  = wg >> 5;        // 0..7  cohort (32 rows)
  const unsigned cg  = wg & 31u;       // 0..31 col group (32 cols)
  const unsigned lo5 = l & 31u;
  const unsigned hi  = l >> 5;
  const unsigned cw    = w & 3u;       // c-group for cell
  const unsigned ihalf = w >> 2;       // which half of the float4

  // ---- register-resident W fragments (36 x int4 = 144 regs) ----
  int4 Braw[4][9];
  {
    const int4* wpv = (const int4*)wp;
    const unsigned wbase = (cg * 8u + w) * 2304u;  // 4*9*64 int4 per (cg,w)
#pragma unroll
    for (int n = 0; n < 4; ++n) {
#pragma unroll
      for (int q = 0; q < 9; ++q) {
        Braw[n][q] = wpv[wbase + (unsigned)(n * 9 + q) * 64u + l];
      }
    }
  }

  float bias_v[4];
#pragma unroll
  for (int n = 0; n < 4; ++n) bias_v[n] = bias[(unsigned)n * 1024u + cg * 32u + lo5];

  // cell rows: r0 + {0,1}, col = cg*32 + lo5
  const unsigned r0 = 8u * cw + 4u * hi + 2u * ihalf;
  float c_st[2];
  unsigned soff[2];
#pragma unroll
  for (int i = 0; i < 2; ++i) {
    soff[i] = (rg * 32u + r0 + (unsigned)i) * 1024u + cg * 32u + lo5;
    c_st[i] = c0[soff[i]];
  }

  // consumer fragment addressing: chunk 8w+q at rg*65536 + chunk*1024 + l*16
  const unsigned fragbase = rg * 65536u + (w * 8u) * 1024u + l * 16u;
  // x: lane l -> b = rg*32 + (l&31), f = w*16 + (l>>5)*8 ; +65536/step
  unsigned xb = (rg * 32u + lo5) * 256u + (w * 16u + hi * 8u) * 2u;

  const char* xbase = (const char*)xT;
  const char* hbase = (const char*)hb;
  unsigned* flags = &bar[rg * 32u];    // 32 epoch flags, one 128B line

  // producer fragment write: thread -> (q=tid>>8, pl=(tid>>2)&63, p=tid&3)
  const unsigned pq = tid >> 8;
  const unsigned pl = (tid >> 2) & 63u;
  const unsigned pp = tid & 3u;
  const unsigned plc = pq * 16u + (pl >> 5) * 8u + pp * 2u;
  const unsigned hst_rd = (pl & 31u) * 64u + plc * 2u;   // byte in hst
  const unsigned pw_off = rg * 65536u + (cg * 2u + pq) * 1024u + pl * 16u + pp * 4u;

  int4 xr;
  xr = *(const int4*)(xbase + xb);

  for (unsigned t = 0; t < 256u; ++t) {
    const char* hrd = hbase + ((t & 3u) * 524288u);
    char* hwr = (char*)hbase + (((t + 1u) & 3u) * 524288u);

    // ---- preload first 4 h fragment chunks (direct to registers) ----
    int4 ah[4];
#pragma unroll
    for (int q = 0; q < 4; ++q)
      ah[q] = load_frag(hrd + fragbase + (unsigned)q * 1024u);

    f32x16 acc[4] = {};
    // x chunk (q=8) while h loads are in flight
    {
      f16x8 a = __builtin_bit_cast(f16x8, xr);
      acc[0] = __builtin_amdgcn_mfma_f32_32x32x16_f16(a, __builtin_bit_cast(f16x8, Braw[0][8]), acc[0], 0, 0, 0);
      acc[1] = __builtin_amdgcn_mfma_f32_32x32x16_f16(a, __builtin_bit_cast(f16x8, Braw[1][8]), acc[1], 0, 0, 0);
      acc[2] = __builtin_amdgcn_mfma_f32_32x32x16_f16(a, __builtin_bit_cast(f16x8, Braw[2][8]), acc[2], 0, 0, 0);
      acc[3] = __builtin_amdgcn_mfma_f32_32x32x16_f16(a, __builtin_bit_cast(f16x8, Braw[3][8]), acc[3], 0, 0, 0);
    }
    // ---- 8 h chunks, rolling 4-deep ----
#pragma unroll
    for (int q = 0; q < 8; ++q) {
      f16x8 a = __builtin_bit_cast(f16x8, ah[q & 3]);
      if (q + 4 < 8)
        ah[q & 3] = load_frag(hrd + fragbase + (unsigned)(q + 4) * 1024u);
      acc[0] = __builtin_amdgcn_mfma_f32_32x32x16_f16(a, __builtin_bit_cast(f16x8, Braw[0][q]), acc[0], 0, 0, 0);
      acc[1] = __builtin_amdgcn_mfma_f32_32x32x16_f16(a, __builtin_bit_cast(f16x8, Braw[1][q]), acc[1], 0, 0, 0);
      acc[2] = __builtin_amdgcn_mfma_f32_32x32x16_f16(a, __builtin_bit_cast(f16x8, Braw[2][q]), acc[2], 0, 0, 0);
      acc[3] = __builtin_amdgcn_mfma_f32_32x32x16_f16(a, __builtin_bit_cast(f16x8, Braw[3][q]), acc[3], 0, 0, 0);
    }

    // ---- 8-wave reduction: write all accs (128KB) ----
#pragma unroll
    for (int n = 0; n < 4; ++n) {
#pragma unroll
      for (int c = 0; c < 4; ++c) {
        float4 v;
        v.x = acc[n][4 * c + 0]; v.y = acc[n][4 * c + 1];
        v.z = acc[n][4 * c + 2]; v.w = acc[n][4 * c + 3];
        redv[((w * 4u + (unsigned)n) * 4u + (unsigned)c) * 64u + l] = v;
      }
    }
    __syncthreads();  // (A) reduce buffer complete

    float gv[4][2];
#pragma unroll
    for (int n = 0; n < 4; ++n) {
      float s0 = bias_v[n], s1 = bias_v[n];
#pragma unroll
      for (int wo = 0; wo < 8; ++wo) {
        float2 v = redv2[((((unsigned)wo * 4u + (unsigned)n) * 4u + cw) * 64u + l) * 2u + ihalf];
        s0 += v.x; s1 += v.y;
      }
      gv[n][0] = s0; gv[n][1] = s1;
    }

    // ---- per-thread LSTM cell update (2 rows) ----
    const bool last = (t == 255u);
#pragma unroll
    for (int i = 0; i < 2; ++i) {
      float ig = fast_sig(gv[0][i]);
      float fg = fast_sig(gv[1][i]);
      float gg = fast_tanh(gv[2][i]);
      float og = fast_sig(gv[3][i]);
      float cc = fg * c_st[i] + ig * gg;
      c_st[i] = cc;
      float hh = og * fast_tanh(cc);
      hst[(r0 + (unsigned)i) * 32u + lo5] = f2h(hh);
      if (last) sigh[soff[i]] = fast_sig(hh);
    }

    if (!last) {
      __syncthreads();  // (B) hst tile complete
      // ---- producer fragment write: 512 x 4B coalesced agent stores ----
      {
        unsigned v = *(const unsigned*)((const char*)hst + hst_rd);
        __hip_atomic_store((unsigned*)(hwr + pw_off), v, __ATOMIC_RELAXED, SCOPE_AGENT);
      }
      // prefetch next step's x fragment
      xb += 65536u;
      xr = *(const int4*)(xbase + xb);
      // (C) barrier lowering waits vmcnt(0): all h stores ACKed at MALL
      __syncthreads();
      if (tid == 0)
        __hip_atomic_store(&flags[cg], t + 1u, __ATOMIC_RELAXED, SCOPE_AGENT);
      // ---- per-wave poll: only this wave's 4 producers ----
      {
        const unsigned tgt = t + 1u;
        const unsigned fidx = w * 4u + (l & 3u);
        for (;;) {
          unsigned f = __hip_atomic_load(&flags[fidx], __ATOMIC_RELAXED, SCOPE_AGENT);
          if (__all(f >= tgt)) break;
          __builtin_amdgcn_s_sleep(1);
        }
      }
    }
  }
}

// out[b][o] = b_fc[o] + sum_k sigh[b][k] * W_fc[o][k]
__global__ void final_fc(const float* __restrict__ sigh, const float* __restrict__ W_fc,
                         const float* __restrict__ b_fc, float* __restrict__ out) {
  unsigned b = blockIdx.x;
  unsigned o = threadIdx.x;
  const float* hrow = sigh + (size_t)b * 1024u;
  const float* wrow = W_fc + (size_t)o * 1024u;
  float acc = b_fc[o];
#pragma unroll 8
  for (unsigned k = 0; k < 1024u; k += 4u) {
    float4 hv = *(const float4*)(hrow + k);
    float4 wv = *(const float4*)(wrow + k);
    acc += hv.x * wv.x + hv.y * wv.y + hv.z * wv.z + hv.w * wv.w;
  }
  out[b * 128u + o] = acc;
}

extern "C" void kernel_launch(void* const* d_in, const int* in_sizes, int n_in,
                              void* d_out, int out_size, void* d_ws, size_t ws_size,
                              hipStream_t stream) {
  (void)in_sizes; (void)n_in; (void)out_size; (void)ws_size;
  const float* x    = (const float*)d_in[0];
  const float* h0   = (const float*)d_in[1];
  const float* c0   = (const float*)d_in[2];
  const float* W_ih = (const float*)d_in[3];
  const float* W_hh = (const float*)d_in[4];
  const float* b_ih = (const float*)d_in[5];
  const float* b_hh = (const float*)d_in[6];
  const float* W_fc = (const float*)d_in[7];
  const float* b_fc = (const float*)d_in[8];

  char* ws = (char*)d_ws;
  unsigned short* wp   = (unsigned short*)(ws + WS_WP);
  float*          bias = (float*)(ws + WS_BIAS);
  unsigned short* xT   = (unsigned short*)(ws + WS_XT);
  unsigned short* hb   = (unsigned short*)(ws + WS_HB);
  float*          sigh = (float*)(ws + WS_SIGH);
  unsigned*       bar  = (unsigned*)(ws + WS_BAR);
  float*          out  = (float*)d_out;

  prep_pack<<<18432, 256, 0, stream>>>(W_ih, W_hh, b_ih, b_hh, wp, bias);
  prep_misc<<<32768, 256, 0, stream>>>(x, h0, xT, hb, bar);
  lstm_main<<<256, 512, 133120, stream>>>(wp, bias, xT, hb, c0, sigh, bar);
  final_fc<<<256, 128, 0, stream>>>(sigh, W_fc, b_fc, out);
}